// Round 2
// baseline (502.924 us; speedup 1.0000x reference)
//
#include <hip/hip_runtime.h>

// CharAttention: per (b,w) causal char-attention; only row x_end_idx[b,w]
// survives the gather -> compute only that row.
//   q = x[qidx] @ Wq (1x32); k,v = x[0..qidx] @ Wk,Wv (Lx32);
//   s[h][j] = (q_h . k_{j,h})/4, softmax j<=qidx; o = p @ v;
//   out = x[qidx] + o @ Wproj.
//
// Persistent 4-wave blocks. One wave per problem, grid-stride loop.
// Weights: wkv columns in registers (loaded once/wave); wq/wproj in block
// LDS (staged once/block). x rows read directly from global via
// wave-uniform addresses (broadcast / SMEM candidates). Wave-local
// lgkmcnt fences instead of __syncthreads so waves with different L
// never couple.

#define CB      24
#define CC      32
#define DD      16
#define THREEC  96
#define NBW     (512 * 128)
#define NBLOCKS 1536
#define WPB     4
#define TOTAL_WAVES (NBLOCKS * WPB)

struct __align__(16) WaveSmem {
    float ks[CB][36];   // k cols 0..31, rows padded to 144 B (16B-aligned)
    float qs[CC];       // q row (pre-scaled by 0.25)
    float ps[2][CC];    // softmax probs per head (j>=L slots are 0)
    float os[CC];       // attention output row
};                      // 3968 B per wave

__device__ __forceinline__ void wave_fence() {
    __asm__ volatile("s_waitcnt lgkmcnt(0)" ::: "memory");
}

__global__ __launch_bounds__(256, 6) void char_attn_kernel(
    const float* __restrict__ x,        // [B*W, 24, 32]
    const int*   __restrict__ xend,     // [B*W]
    const float* __restrict__ w_attn,   // [32, 96]
    const float* __restrict__ w_proj,   // [32, 32]
    float*       __restrict__ out)      // [B*W, 32]
{
    __shared__ float wqs[CC][CC];       // w_attn[:, 0:32]   (4 KB)
    __shared__ float wps[CC][CC];       // w_proj            (4 KB)
    __shared__ WaveSmem sm[WPB];        // 15872 B -> 24 KB total/block

    const int tid  = threadIdx.x;
    const int lane = tid & 63;
    const int wave = __builtin_amdgcn_readfirstlane(tid >> 6);
    WaveSmem& S = sm[wave];

    // ---- stage q/proj weights once per block ----
    for (int t = tid; t < CC * CC; t += 256) {
        const int c = t >> 5, i = t & 31;
        wqs[c][i] = w_attn[c * THREEC + i];
        wps[c][i] = w_proj[t];
    }
    __syncthreads();

    // ---- per-lane k/v weight column, loaded once ----
    // lane<32: k col = w_attn[:,32+lane]; lane>=32: v col = w_attn[:,32+lane].
    float wkv[CC];
    #pragma unroll
    for (int c = 0; c < CC; ++c) wkv[c] = w_attn[c * THREEC + CC + lane];

    const int i32  = lane & 31;
    const int half = lane >> 5;

    float vreg[CB];
    #pragma unroll
    for (int j = 0; j < CB; ++j) vreg[j] = 0.f;   // keep products finite

    const int wgid = blockIdx.x * WPB + wave;      // wave-uniform

    for (int bid = wgid; bid < NBW; bid += TOTAL_WAVES) {
        const int qidx = xend[bid];               // uniform scalar load
        const int L    = qidx + 1;
        const float* xb = x + (size_t)bid * (CB * CC);

        // ---- kv: k[j][.] -> LDS, v[j][.] -> regs (lane = column) ----
        #pragma unroll
        for (int j = 0; j < CB; ++j) {
            if (j < L) {                          // wave-uniform guard
                const float4* xr = (const float4*)(xb + j * CC);
                float a0 = 0.f, a1 = 0.f, a2 = 0.f, a3 = 0.f;
                #pragma unroll
                for (int c4 = 0; c4 < 8; c4 += 4) {
                    float4 r0 = xr[c4 + 0], r1 = xr[c4 + 1];
                    float4 r2 = xr[c4 + 2], r3 = xr[c4 + 3];
                    const int c = c4 * 4;
                    a0 = fmaf(r0.x, wkv[c + 0], a0);  a1 = fmaf(r0.y, wkv[c + 1], a1);
                    a2 = fmaf(r0.z, wkv[c + 2], a2);  a3 = fmaf(r0.w, wkv[c + 3], a3);
                    a0 = fmaf(r1.x, wkv[c + 4], a0);  a1 = fmaf(r1.y, wkv[c + 5], a1);
                    a2 = fmaf(r1.z, wkv[c + 6], a2);  a3 = fmaf(r1.w, wkv[c + 7], a3);
                    a0 = fmaf(r2.x, wkv[c + 8], a0);  a1 = fmaf(r2.y, wkv[c + 9], a1);
                    a2 = fmaf(r2.z, wkv[c + 10], a2); a3 = fmaf(r2.w, wkv[c + 11], a3);
                    a0 = fmaf(r3.x, wkv[c + 12], a0); a1 = fmaf(r3.y, wkv[c + 13], a1);
                    a2 = fmaf(r3.z, wkv[c + 14], a2); a3 = fmaf(r3.w, wkv[c + 15], a3);
                }
                const float acc = (a0 + a1) + (a2 + a3);
                if (lane < CC) S.ks[j][lane] = acc;
                else           vreg[j]      = acc;
            }
        }

        // ---- q row, split across both halves: 16 MACs each + xor-32 ----
        {
            const float4* xq = (const float4*)(xb + qidx * CC);
            float a0 = 0.f, a1 = 0.f;
            #pragma unroll
            for (int c4 = 0; c4 < 4; ++c4) {
                float4 r = xq[half * 4 + c4];
                const int c = half * 16 + c4 * 4;
                a0 = fmaf(r.x, wqs[c + 0][i32], a0);
                a1 = fmaf(r.y, wqs[c + 1][i32], a1);
                a0 = fmaf(r.z, wqs[c + 2][i32], a0);
                a1 = fmaf(r.w, wqs[c + 3][i32], a1);
            }
            float t = a0 + a1;
            t += __shfl_xor(t, 32);
            if (lane < CC) S.qs[i32] = t * 0.25f;   // fold 1/sqrt(D)
        }

        wave_fence();   // ks + qs visible

        // ---- scores + softmax: lane -> (h = lane>>5, j = lane&31) ----
        {
            const int j2 = i32;
            float s = -INFINITY;
            if (j2 <= qidx) {
                const float4* kr = (const float4*)&S.ks[j2][half * DD];
                const float4* qr = (const float4*)&S.qs[half * DD];
                float a0 = 0.f, a1 = 0.f;
                #pragma unroll
                for (int t = 0; t < 4; ++t) {
                    float4 kk = kr[t], qq = qr[t];
                    a0 = fmaf(kk.x, qq.x, a0);
                    a1 = fmaf(kk.y, qq.y, a1);
                    a0 = fmaf(kk.z, qq.z, a0);
                    a1 = fmaf(kk.w, qq.w, a1);
                }
                s = a0 + a1;                        // scale already in qs
            }
            float m = s;
            #pragma unroll
            for (int off = 16; off >= 1; off >>= 1)
                m = fmaxf(m, __shfl_xor(m, off));
            const float e = (j2 <= qidx) ? __expf(s - m) : 0.f;
            float sum = e;
            #pragma unroll
            for (int off = 16; off >= 1; off >>= 1)
                sum += __shfl_xor(sum, off);
            S.ps[half][j2] = e / sum;               // 0 for masked j
        }

        wave_fence();   // ps visible

        // ---- att @ v (lanes 32..63 hold v columns; masked probs are 0) ----
        if (lane >= CC) {
            const int dp = lane - CC;
            const int h  = dp >> 4;
            const float4* pr = (const float4*)S.ps[h];
            float a0 = 0.f, a1 = 0.f;
            #pragma unroll
            for (int t = 0; t < 6; ++t) {
                float4 p4 = pr[t];
                a0 = fmaf(p4.x, vreg[4 * t + 0], a0);
                a1 = fmaf(p4.y, vreg[4 * t + 1], a1);
                a0 = fmaf(p4.z, vreg[4 * t + 2], a0);
                a1 = fmaf(p4.w, vreg[4 * t + 3], a1);
            }
            S.os[dp] = a0 + a1;
        }

        wave_fence();   // os visible

        // ---- proj + residual, split across halves + xor-32 ----
        {
            const float4* o4 = (const float4*)S.os;
            float a0 = 0.f, a1 = 0.f;
            #pragma unroll
            for (int c4 = 0; c4 < 4; ++c4) {
                float4 o = o4[half * 4 + c4];
                const int c = half * 16 + c4 * 4;
                a0 = fmaf(o.x, wps[c + 0][i32], a0);
                a1 = fmaf(o.y, wps[c + 1][i32], a1);
                a0 = fmaf(o.z, wps[c + 2][i32], a0);
                a1 = fmaf(o.w, wps[c + 3][i32], a1);
            }
            float t = a0 + a1;
            t += __shfl_xor(t, 32);
            if (lane < CC)
                out[(size_t)bid * CC + lane] = t + xb[qidx * CC + lane];
        }

        wave_fence();   // drain before next iteration reuses LDS
    }
}

extern "C" void kernel_launch(void* const* d_in, const int* in_sizes, int n_in,
                              void* d_out, int out_size, void* d_ws, size_t ws_size,
                              hipStream_t stream) {
    const float* x      = (const float*)d_in[0];
    const int*   xend   = (const int*)d_in[1];
    const float* w_attn = (const float*)d_in[2];
    const float* w_proj = (const float*)d_in[3];
    float* out = (float*)d_out;

    char_attn_kernel<<<dim3(NBLOCKS), dim3(256), 0, stream>>>(x, xend, w_attn, w_proj, out);
}

// Round 3
// 494.957 us; speedup vs baseline: 1.0161x; 1.0161x over previous
//
#include <hip/hip_runtime.h>

// CharAttention: per (b,w) causal char-attention; only row x_end_idx[b,w]
// survives the gather -> compute only that row.
//   q = x[qidx] @ Wq (1x32); k,v = x[0..qidx] @ Wk,Wv (Lx32);
//   s[h][j] = (q_h . k_{j,h})/4, softmax j<=qidx; o = p @ v;
//   out = x[qidx] + o @ Wproj.
//
// One wave per problem, 4 waves per block (grid 16384), NO persistent loop
// (round-2's persistent version spilled: WRITE_SIZE 62MB of scratch).
// Only wkv[32] lives in registers; k AND v go to LDS so VGPR fits the
// __launch_bounds__(256,6) cap (85) without spilling. k is stored
// transposed with +1 pad (odd stride 25 -> conflict-free on both the
// column write and the j-strided score reads). LDS = 27,136 B/block ->
// 6 blocks/CU -> 24 waves/CU (75% occupancy vs round-1's 50%).

#define CB      24
#define CC      32
#define DD      16
#define THREEC  96
#define NBW     (512 * 128)
#define WPB     4

struct __align__(16) WaveSmem {
    float ksT[CC][CB + 1];  // k transposed: ksT[i][j], odd stride 25 (3200 B)
    float vs[CB][CC];       // v row-major (3072 B)
    float qs[CC];           // q row, pre-scaled by 0.25 (128 B)
    float ps[2][CC];        // softmax probs per head; masked slots = 0 (256 B)
    float os[CC];           // attention output row (128 B)
};                          // 6784 B per wave -> 27136 B per block

__device__ __forceinline__ void wave_fence() {
    __asm__ volatile("s_waitcnt lgkmcnt(0)" ::: "memory");
}

__global__ __launch_bounds__(256, 6) void char_attn_kernel(
    const float* __restrict__ x,        // [B*W, 24, 32]
    const int*   __restrict__ xend,     // [B*W]
    const float* __restrict__ w_attn,   // [32, 96]
    const float* __restrict__ w_proj,   // [32, 32]
    float*       __restrict__ out)      // [B*W, 32]
{
    __shared__ WaveSmem sm[WPB];

    const int tid  = threadIdx.x;
    const int lane = tid & 63;
    const int wave = tid >> 6;
    WaveSmem& S = sm[wave];

    const int bid  = blockIdx.x * WPB + wave;   // one problem per wave
    const int i32  = lane & 31;
    const int half = lane >> 5;

    // ---- per-lane k/v weight column of w_attn (loaded once) ----
    // lane<32: k col lane = w_attn[:,32+lane]; lane>=32: v col = same index.
    float wkv[CC];
    #pragma unroll
    for (int c = 0; c < CC; ++c) wkv[c] = w_attn[c * THREEC + CC + lane];

    const int qidx = xend[bid];                 // wave-uniform scalar load
    const int L    = qidx + 1;
    const float* xb = x + (size_t)bid * (CB * CC);

    // ---- kv: lane<32 -> ksT[lane][j], lane>=32 -> vs[j][lane-32] ----
    // Per-lane write cursor: stride 1 for kT columns, 32 for v rows.
    float* wp = (lane < CC) ? &S.ksT[lane][0] : &S.vs[0][lane - CC];
    const int wstep = (lane < CC) ? 1 : CC;

    #pragma unroll
    for (int j = 0; j < CB; ++j) {
        float val = 0.f;                         // rows >= L zero-filled
        if (j < L) {                             // wave-uniform guard
            const float4* xr = (const float4*)(xb + j * CC);
            float a0 = 0.f, a1 = 0.f, a2 = 0.f, a3 = 0.f;
            #pragma unroll
            for (int c4 = 0; c4 < 8; c4 += 4) {
                float4 r0 = xr[c4 + 0], r1 = xr[c4 + 1];
                float4 r2 = xr[c4 + 2], r3 = xr[c4 + 3];
                const int c = c4 * 4;
                a0 = fmaf(r0.x, wkv[c + 0], a0);  a1 = fmaf(r0.y, wkv[c + 1], a1);
                a2 = fmaf(r0.z, wkv[c + 2], a2);  a3 = fmaf(r0.w, wkv[c + 3], a3);
                a0 = fmaf(r1.x, wkv[c + 4], a0);  a1 = fmaf(r1.y, wkv[c + 5], a1);
                a2 = fmaf(r1.z, wkv[c + 6], a2);  a3 = fmaf(r1.w, wkv[c + 7], a3);
                a0 = fmaf(r2.x, wkv[c + 8], a0);  a1 = fmaf(r2.y, wkv[c + 9], a1);
                a2 = fmaf(r2.z, wkv[c + 10], a2); a3 = fmaf(r2.w, wkv[c + 11], a3);
                a0 = fmaf(r3.x, wkv[c + 12], a0); a1 = fmaf(r3.y, wkv[c + 13], a1);
                a2 = fmaf(r3.z, wkv[c + 14], a2); a3 = fmaf(r3.w, wkv[c + 15], a3);
            }
            val = (a0 + a1) + (a2 + a3);
        }
        *wp = val;
        wp += wstep;
    }

    // ---- q row, split across halves (16 MACs each) + xor-32 combine ----
    {
        const float4* xq = (const float4*)(xb + qidx * CC);
        float a0 = 0.f, a1 = 0.f;
        #pragma unroll
        for (int c4 = 0; c4 < 4; ++c4) {
            float4 r = xq[half * 4 + c4];
            const int c = half * DD + c4 * 4;
            a0 = fmaf(r.x, w_attn[(c + 0) * THREEC + i32], a0);
            a1 = fmaf(r.y, w_attn[(c + 1) * THREEC + i32], a1);
            a0 = fmaf(r.z, w_attn[(c + 2) * THREEC + i32], a0);
            a1 = fmaf(r.w, w_attn[(c + 3) * THREEC + i32], a1);
        }
        float t = a0 + a1;
        t += __shfl_xor(t, 32);
        if (lane < CC) S.qs[i32] = t * 0.25f;    // fold 1/sqrt(D)
    }

    wave_fence();   // ksT + vs + qs visible within the wave

    // ---- scores + softmax: lane -> (h = half, j = i32) ----
    {
        float s = -INFINITY;
        if (i32 <= qidx) {
            const float4* qr = (const float4*)&S.qs[half * DD];
            float a0 = 0.f, a1 = 0.f;
            #pragma unroll
            for (int t = 0; t < 4; ++t) {
                float4 qq = qr[t];
                const int r = half * DD + 4 * t;
                a0 = fmaf(S.ksT[r + 0][i32], qq.x, a0);
                a1 = fmaf(S.ksT[r + 1][i32], qq.y, a1);
                a0 = fmaf(S.ksT[r + 2][i32], qq.z, a0);
                a1 = fmaf(S.ksT[r + 3][i32], qq.w, a1);
            }
            s = a0 + a1;                          // scale folded into qs
        }
        float m = s;
        #pragma unroll
        for (int off = 16; off >= 1; off >>= 1)
            m = fmaxf(m, __shfl_xor(m, off));
        const float e = (i32 <= qidx) ? __expf(s - m) : 0.f;
        float sum = e;
        #pragma unroll
        for (int off = 16; off >= 1; off >>= 1)
            sum += __shfl_xor(sum, off);
        S.ps[half][i32] = e / sum;                // 0 for masked j
    }

    wave_fence();   // ps visible

    // ---- att @ v: output dp = i32, j-range split across halves ----
    // vs rows >= L are zero-filled and ps masked slots are 0, so no guard.
    {
        const int h = i32 >> 4;                   // head of output dim
        float acc = 0.f;
        #pragma unroll
        for (int t = 0; t < 12; ++t) {
            const int j = half * 12 + t;
            acc = fmaf(S.ps[h][j], S.vs[j][i32], acc);
        }
        acc += __shfl_xor(acc, 32);
        if (lane < CC) S.os[i32] = acc;
    }

    wave_fence();   // os visible

    // ---- proj + residual, split across halves + xor-32 ----
    {
        const float4* o4 = (const float4*)&S.os[half * DD];
        float a0 = 0.f, a1 = 0.f;
        #pragma unroll
        for (int c4 = 0; c4 < 4; ++c4) {
            float4 o = o4[c4];
            const int c = half * DD + c4 * 4;
            a0 = fmaf(o.x, w_proj[(c + 0) * CC + i32], a0);
            a1 = fmaf(o.y, w_proj[(c + 1) * CC + i32], a1);
            a0 = fmaf(o.z, w_proj[(c + 2) * CC + i32], a0);
            a1 = fmaf(o.w, w_proj[(c + 3) * CC + i32], a1);
        }
        float t = a0 + a1;
        t += __shfl_xor(t, 32);
        if (lane < CC)
            out[(size_t)bid * CC + i32] = t + xb[qidx * CC + i32];
    }
}

extern "C" void kernel_launch(void* const* d_in, const int* in_sizes, int n_in,
                              void* d_out, int out_size, void* d_ws, size_t ws_size,
                              hipStream_t stream) {
    const float* x      = (const float*)d_in[0];
    const int*   xend   = (const int*)d_in[1];
    const float* w_attn = (const float*)d_in[2];
    const float* w_proj = (const float*)d_in[3];
    float* out = (float*)d_out;

    char_attn_kernel<<<dim3(NBW / WPB), dim3(WPB * 64), 0, stream>>>(
        x, xend, w_attn, w_proj, out);
}

// Round 4
// 302.411 us; speedup vs baseline: 1.6631x; 1.6367x over previous
//
#include <hip/hip_runtime.h>

// CharAttention: per (b,w) causal char-attention; only row x_end_idx[b,w]
// survives the final gather -> compute only that row, AND fold the single
// query through the weights so K and V are never materialized:
//   q            = x[qidx] @ Wq                       (1x32)
//   rk_h[c]      = 0.25 * sum_d Wk[c][16h+d] q[16h+d] (2x32)   <- replaces K
//   s[h][j]      = x[j] . rk_h        (j <= qidx)
//   p            = softmax(s)
//   y_h[c]       = sum_j p[h][j] x[j][c]              (2x32)   <- replaces V
//   o[i]         = y_{i>>4} . Wv[:,i]                 (1x32)
//   out          = x[qidx] + o @ Wproj
// Per-problem MACs: 4096 + 128*L (~5.7K avg) vs ~49K for explicit K/V.
// Kernel becomes HBM/latency bound (prefix fetch ~52MB + 8MB write -> ~10us floor).
//
// One wave per problem, 4 waves per 256-thread block, grid 16384.
// LDS 17.2KB/block -> 8 blocks/CU -> 32 waves/CU (100% occupancy).
// All cross-lane traffic is wave-local -> lgkmcnt fences, no __syncthreads.

#define CB      24
#define CC      32
#define DD      16
#define THREEC  96
#define NBW     (512 * 128)
#define WPB     4
#define XSS     34              // xs row stride: even (float2-aligned), 2-way banks max

struct __align__(16) WaveSmem {
    float xs[CB][XSS];          // staged x rows (3264 B)
    float rks[2][CC];           // rk per head, scale folded (256 B)
    float ps[2][CC];            // softmax probs; masked slots 0 (256 B)
    float ys[2][CC];            // p @ x per head (256 B)
    float os[CC];               // attention output row (128 B)
    float pad[2];               // keep 16B multiple
};                              // 4168 B -> 4 waves = ~16.7 KB/block

__device__ __forceinline__ void wave_fence() {
    __asm__ volatile("s_waitcnt lgkmcnt(0)" ::: "memory");
}

__global__ __launch_bounds__(256, 8) void char_attn_kernel(
    const float* __restrict__ x,        // [B*W, 24, 32]
    const int*   __restrict__ xend,     // [B*W]
    const float* __restrict__ w_attn,   // [32, 96]
    const float* __restrict__ w_proj,   // [32, 32]
    float*       __restrict__ out)      // [B*W, 32]
{
    __shared__ WaveSmem sm[WPB];

    const int tid  = threadIdx.x;
    const int lane = tid & 63;
    const int wave = tid >> 6;
    WaveSmem& S = sm[wave];

    const int bid  = blockIdx.x * WPB + wave;   // one problem per wave
    const int i32  = lane & 31;
    const int half = lane >> 5;

    const int qidx = xend[bid];                 // wave-uniform scalar load
    const int L    = qidx + 1;
    const float* xb = x + (size_t)bid * (CB * CC);

    // ---- stage x rows 0..qidx into LDS (coalesced float2) ----
    {
        const float2* xb2 = (const float2*)xb;
        const int n2 = L * (CC / 2);            // <= 384
        for (int t = lane; t < n2; t += 64) {
            float2 v = xb2[t];
            const int r = t >> 4, c = (t & 15) * 2;
            *(float2*)&S.xs[r][c] = v;          // 8B-aligned (XSS even)
        }
    }
    wave_fence();                               // xs visible in-wave

    // ---- q[i] (half-split over c) -> every lane holds q[i32] ----
    float qv;
    {
        const int cb = half * DD;
        float a0 = 0.f, a1 = 0.f;
        #pragma unroll
        for (int t = 0; t < DD; t += 2) {
            a0 = fmaf(S.xs[qidx][cb + t],     w_attn[(cb + t) * THREEC + i32],     a0);
            a1 = fmaf(S.xs[qidx][cb + t + 1], w_attn[(cb + t + 1) * THREEC + i32], a1);
        }
        qv = a0 + a1;
        qv += __shfl_xor(qv, 32);               // q[i32] in all 64 lanes
    }

    // ---- rk: lane=(c=i32, h=half): rks[h][c] = 0.25 * Wk[c][h,:].q_h ----
    {
        const float4* w4 = (const float4*)&w_attn[i32 * THREEC + CC + DD * half];
        float4 w0 = w4[0], w1 = w4[1], w2 = w4[2], w3 = w4[3];
        const int db = DD * half;
        float a0 = 0.f, a1 = 0.f;
        a0 = fmaf(w0.x, __shfl(qv, db + 0),  a0); a1 = fmaf(w0.y, __shfl(qv, db + 1),  a1);
        a0 = fmaf(w0.z, __shfl(qv, db + 2),  a0); a1 = fmaf(w0.w, __shfl(qv, db + 3),  a1);
        a0 = fmaf(w1.x, __shfl(qv, db + 4),  a0); a1 = fmaf(w1.y, __shfl(qv, db + 5),  a1);
        a0 = fmaf(w1.z, __shfl(qv, db + 6),  a0); a1 = fmaf(w1.w, __shfl(qv, db + 7),  a1);
        a0 = fmaf(w2.x, __shfl(qv, db + 8),  a0); a1 = fmaf(w2.y, __shfl(qv, db + 9),  a1);
        a0 = fmaf(w2.z, __shfl(qv, db + 10), a0); a1 = fmaf(w2.w, __shfl(qv, db + 11), a1);
        a0 = fmaf(w3.x, __shfl(qv, db + 12), a0); a1 = fmaf(w3.y, __shfl(qv, db + 13), a1);
        a0 = fmaf(w3.z, __shfl(qv, db + 14), a0); a1 = fmaf(w3.w, __shfl(qv, db + 15), a1);
        S.rks[half][i32] = (a0 + a1) * 0.25f;   // fold 1/sqrt(D)
    }
    wave_fence();                               // rks visible

    // ---- scores + softmax: lane=(h=half, j=i32) ----
    {
        float sc = -INFINITY;
        if (i32 <= qidx) {
            float a0 = 0.f, a1 = 0.f;
            #pragma unroll
            for (int c = 0; c < CC; c += 2) {
                a0 = fmaf(S.xs[i32][c],     S.rks[half][c],     a0);
                a1 = fmaf(S.xs[i32][c + 1], S.rks[half][c + 1], a1);
            }
            sc = a0 + a1;
        }
        float m = sc;
        #pragma unroll
        for (int off = 16; off >= 1; off >>= 1)
            m = fmaxf(m, __shfl_xor(m, off));
        const float e = (i32 <= qidx) ? __expf(sc - m) : 0.f;
        float sum = e;
        #pragma unroll
        for (int off = 16; off >= 1; off >>= 1)
            sum += __shfl_xor(sum, off);
        S.ps[half][i32] = e / sum;              // 0 for masked j
    }
    wave_fence();                               // ps visible

    // ---- y: lane=(c=i32, h=half): ys[h][c] = sum_j p[h][j] xs[j][c] ----
    {
        float acc = 0.f;
        for (int j = 0; j < L; ++j)             // wave-uniform trip count
            acc = fmaf(S.ps[half][j], S.xs[j][i32], acc);
        S.ys[half][i32] = acc;
    }
    wave_fence();                               // ys visible

    // ---- o[i] = y_{i>>4} . Wv[:,i], half-split over c ----
    {
        const int hi = i32 >> 4;                // head of output dim
        const int cb = half * DD;
        float a0 = 0.f, a1 = 0.f;
        #pragma unroll
        for (int t = 0; t < DD; t += 2) {
            a0 = fmaf(S.ys[hi][cb + t],     w_attn[(cb + t) * THREEC + 2 * CC + i32],     a0);
            a1 = fmaf(S.ys[hi][cb + t + 1], w_attn[(cb + t + 1) * THREEC + 2 * CC + i32], a1);
        }
        float t = a0 + a1;
        t += __shfl_xor(t, 32);
        if (lane < CC) S.os[i32] = t;
    }
    wave_fence();                               // os visible

    // ---- proj + residual, half-split over c + xor-32 combine ----
    {
        const int cb = half * DD;
        float a0 = 0.f, a1 = 0.f;
        #pragma unroll
        for (int t = 0; t < DD; t += 2) {
            a0 = fmaf(S.os[cb + t],     w_proj[(cb + t) * CC + i32],     a0);
            a1 = fmaf(S.os[cb + t + 1], w_proj[(cb + t + 1) * CC + i32], a1);
        }
        float t = a0 + a1;
        t += __shfl_xor(t, 32);
        if (lane < CC)
            out[(size_t)bid * CC + i32] = t + S.xs[qidx][i32];
    }
}

extern "C" void kernel_launch(void* const* d_in, const int* in_sizes, int n_in,
                              void* d_out, int out_size, void* d_ws, size_t ws_size,
                              hipStream_t stream) {
    const float* x      = (const float*)d_in[0];
    const int*   xend   = (const int*)d_in[1];
    const float* w_attn = (const float*)d_in[2];
    const float* w_proj = (const float*)d_in[3];
    float* out = (float*)d_out;

    char_attn_kernel<<<dim3(NBW / WPB), dim3(WPB * 64), 0, stream>>>(
        x, xend, w_attn, w_proj, out);
}